// Round 2
// baseline (1040.435 us; speedup 1.0000x reference)
//
#include <hip/hip_runtime.h>
#include <hip/hip_bf16.h>
#include <stdint.h>

#define BTOT  65536
#define KTR   11
#define NSLOT 12   // 11 transforms + z

typedef __attribute__((ext_vector_type(8))) short bf16x8_t;
typedef __attribute__((ext_vector_type(4))) float f32x4_t;

// Swizzled LDS layout: row m x 256 bf16 cols, 16B groups rotated by row so
// frag ds_read_b128 across 16 rows spreads banks (<=2-way, free per m136).
// Element offset. b64 sub-writes (n%8 in {0,4}) stay inside one group.
__device__ __forceinline__ int act_addr(int m, int n) {
    return m * 256 + ((((n >> 3) + m) & 31) << 3) + (n & 7);
}

// tanh-form gelu; |err| <~1e-3, invisible under bf16 storage noise.
__device__ __forceinline__ float gelu_fast(float x) {
    float x2 = x * x;
    float t2 = 1.5957691216057308f * x * fmaf(0.044715f, x2, 1.0f);
    float e  = __expf(fminf(t2, 30.f));
    return x * e * __builtin_amdgcn_rcpf(1.0f + e);
}

__global__ void cast_x_kernel(const float* __restrict__ x, __hip_bfloat16* __restrict__ xb) {
    int i = (blockIdx.x * 256 + threadIdx.x) * 4;
    float4 v = *(const float4*)(x + i);
    union { __hip_bfloat16 h[4]; uint64_t u; } o;
    o.h[0] = __float2bfloat16(v.x);
    o.h[1] = __float2bfloat16(v.y);
    o.h[2] = __float2bfloat16(v.z);
    o.h[3] = __float2bfloat16(v.w);
    *(uint64_t*)(xb + i) = o.u;
}

// out[b][c][r] = in[b][r][c], cast fp32 -> bf16.
__global__ void transpose_cast_kernel(const float* __restrict__ in,
                                      __hip_bfloat16* __restrict__ out,
                                      int R, int C) {
    __shared__ float tile[32][33];
    int tpc = C >> 5;
    int tr = (blockIdx.x / tpc) << 5;
    int tc = (blockIdx.x % tpc) << 5;
    const float* bi = in + (size_t)blockIdx.y * R * C;
    __hip_bfloat16* bo = out + (size_t)blockIdx.y * R * C;
    int lx = threadIdx.x & 31, ly = threadIdx.x >> 5;
    #pragma unroll
    for (int r = 0; r < 32; r += 8)
        tile[ly + r][lx] = bi[(size_t)(tr + ly + r) * C + tc + lx];
    __syncthreads();
    #pragma unroll
    for (int r = 0; r < 32; r += 8)
        bo[(size_t)(tc + ly + r) * R + tr + lx] = __float2bfloat16(tile[lx][ly + r]);
}

// One stage: act[64][256] (LDS, swizzled) <- f(act @ W + bias).
// Operand-swapped MFMA: D = W^T (A-op, global L2-hot) x act^T (B-op, LDS).
// D row (q*4+r) = output col n -> 4 consecutive n per thread -> ds_write_b64.
// Wave w owns weight-col strip [w*64, +64) (4 m-tiles) x all 64 batch rows
// (4 n-tiles). M=64 tile: acc=64 AGPR, 32KB LDS -> 3 blocks/CU (12 waves),
// +50% latency hiding vs the M=128 variant (which was 20%-util latency-bound).
__device__ void run_stage(__hip_bfloat16* act,
                          const __hip_bfloat16* __restrict__ Wt,   // [n][k] row-major
                          const float* __restrict__ bias,
                          bool do_gelu, int wave, int lane)
{
    const int lr = lane & 15;
    const int q  = lane >> 4;
    const int wc = wave << 6;           // weight-col strip base

    f32x4_t acc[4][4];
    #pragma unroll
    for (int mt = 0; mt < 4; ++mt)
        #pragma unroll
        for (int nt = 0; nt < 4; ++nt)
            acc[mt][nt] = (f32x4_t){0.f, 0.f, 0.f, 0.f};

    // prefetch A-frags (weights) for kc=0
    bf16x8_t a[4];
    #pragma unroll
    for (int mt = 0; mt < 4; ++mt)
        a[mt] = *(const bf16x8_t*)(Wt + (size_t)(wc + (mt << 4) + lr) * 256 + (q << 3));

    #pragma unroll 1
    for (int kc = 0; kc < 8; ++kc) {
        const int kof = (kc << 5) + (q << 3);
        bf16x8_t an[4];
        if (kc < 7) {
            #pragma unroll
            for (int mt = 0; mt < 4; ++mt)
                an[mt] = *(const bf16x8_t*)(Wt + (size_t)(wc + (mt << 4) + lr) * 256 + kof + 32);
        }
        bf16x8_t b[4];
        #pragma unroll
        for (int nt = 0; nt < 4; ++nt)
            b[nt] = *(const bf16x8_t*)(act + act_addr((nt << 4) + lr, kof));
        #pragma unroll
        for (int mt = 0; mt < 4; ++mt)
            #pragma unroll
            for (int nt = 0; nt < 4; ++nt)
                acc[mt][nt] = __builtin_amdgcn_mfma_f32_16x16x32_bf16(a[mt], b[nt], acc[mt][nt], 0, 0, 0);
        if (kc < 7) {
            #pragma unroll
            for (int mt = 0; mt < 4; ++mt) a[mt] = an[mt];
        }
    }

    __syncthreads();   // all waves done reading act before overwrite
    #pragma unroll
    for (int mt = 0; mt < 4; ++mt) {
        const int nbase = wc + (mt << 4) + (q << 2);
        const float4 bv = *(const float4*)(bias + nbase);
        #pragma unroll
        for (int nt = 0; nt < 4; ++nt) {
            const int row = (nt << 4) + lr;
            union { __hip_bfloat16 h[4]; uint64_t u; } o;
            #pragma unroll
            for (int r = 0; r < 4; ++r) {
                float v = acc[mt][nt][r] + ((const float*)&bv)[r];
                if (do_gelu) v = gelu_fast(v);
                o.h[r] = __float2bfloat16(v);
            }
            *(uint64_t*)(act + act_addr(row, nbase)) = o.u;
        }
    }
    __syncthreads();
}

__launch_bounds__(256, 3)
__global__ void chain_kernel(const __hip_bfloat16* __restrict__ xb,
                             const __hip_bfloat16* __restrict__ Tw1t,
                             const float* __restrict__ Tb1,
                             const __hip_bfloat16* __restrict__ Tw2t,
                             const float* __restrict__ Tb2,
                             const __hip_bfloat16* __restrict__ Ew1t,
                             const float* __restrict__ Eb1,
                             const __hip_bfloat16* __restrict__ Ew2t,
                             const float* __restrict__ Eb2,
                             __hip_bfloat16* __restrict__ zbuf,
                             int b0)
{
    __shared__ __align__(16) __hip_bfloat16 act[64 * 256];   // 32 KB
    const int tid  = threadIdx.x;
    const int wave = tid >> 6, lane = tid & 63;
    const int slot = blockIdx.y;
    const int tile = blockIdx.x;

    // stage x tile (64 rows) into LDS
    #pragma unroll
    for (int i = 0; i < 8; ++i) {
        int lin = i * 256 + tid;
        int r = lin >> 5, g = lin & 31;
        bf16x8_t v = *(const bf16x8_t*)(xb + (size_t)(b0 + tile * 64 + r) * 256 + g * 8);
        *(bf16x8_t*)(act + act_addr(r, g * 8)) = v;
    }
    __syncthreads();

    if (slot < KTR) {
        run_stage(act, Tw1t + (size_t)slot * 65536, Tb1 + slot * 256, true,  wave, lane);
        run_stage(act, Tw2t + (size_t)slot * 65536, Tb2 + slot * 256, false, wave, lane);
    }
    run_stage(act, Ew1t, Eb1, true,  wave, lane);
    run_stage(act, Ew2t, Eb2, false, wave, lane);

    // interleaved zbuf: [row][slot][256]
    __hip_bfloat16* dst = zbuf + ((size_t)(tile * 64) * NSLOT + slot) * 256;
    #pragma unroll
    for (int i = 0; i < 8; ++i) {
        int lin = i * 256 + tid;
        int r = lin >> 5, g = lin & 31;
        bf16x8_t v = *(const bf16x8_t*)(act + act_addr(r, g * 8));
        *(bf16x8_t*)(dst + (size_t)r * NSLOT * 256 + g * 8) = v;
    }
}

// Per row: G = Z Z^T (12x12 over H=256) via mfma(v,v,acc), A-frag == B-frag.
// One row per WAVE, fragments loaded DIRECTLY from global (zbuf's
// [row][slot][256] layout puts a row's whole Gram operand in 6144 contiguous
// bytes; lane(lr,q) reads slot*512 + kc*64 + q*16 -> 64B-granule coalesced,
// full line coverage over the kc loop). No staging LDS, no barrier; only the
// 4.3KB wave-local Gw scratch (within-wave RAW ordered by lgkmcnt, same as
// the previous passing version). Old version: 53.5KB LDS -> 2 blocks/CU,
// block barrier between 48KB stage and divergent tail -> latency-bound ~7x
// over its 402MB HBM roofline.
__launch_bounds__(256, 4)
__global__ void reduce_kernel(const __hip_bfloat16* __restrict__ zbuf,
                              float* __restrict__ out, int b0, int nrows)
{
    __shared__ float Gw[4][16][17];
    const int tid  = threadIdx.x;
    const int wave = tid >> 6, lane = tid & 63;
    const int lr = lane & 15, q = lane >> 4;
    const int slot = lr < NSLOT ? lr : NSLOT - 1;   // lanes 12-15 broadcast slot 11
    const int nw = gridDim.x * 4;                    // total waves
    const size_t lanoff = (size_t)slot * 256 + (q << 3);

    #pragma unroll 1
    for (int r = blockIdx.x * 4 + wave; r < nrows; r += nw) {
        const __hip_bfloat16* zr = zbuf + (size_t)r * (NSLOT * 256) + lanoff;
        bf16x8_t v[8];
        #pragma unroll
        for (int kc = 0; kc < 8; ++kc)
            v[kc] = *(const bf16x8_t*)(zr + kc * 32);

        f32x4_t acc = (f32x4_t){0.f, 0.f, 0.f, 0.f};
        #pragma unroll
        for (int kc = 0; kc < 8; ++kc)
            acc = __builtin_amdgcn_mfma_f32_16x16x32_bf16(v[kc], v[kc], acc, 0, 0, 0);

        #pragma unroll
        for (int rr = 0; rr < 4; ++rr)
            Gw[wave][(q << 2) + rr][lr] = acc[rr];
        // wave-local RAW on Gw: hardware/compiler waitcnt orders it; no barrier
        float term = 0.f;
        if (lane < 11) {
            const int k = lane;
            float n[NSLOT];
            #pragma unroll
            for (int l = 0; l < NSLOT; ++l) n[l] = sqrtf(Gw[wave][l][l]);
            const float nk = n[k];
            float neg = 0.f;
            #pragma unroll
            for (int l = 0; l < KTR; ++l)
                if (l != k)
                    neg += __expf(Gw[wave][l][k] / fmaxf(n[l] * nk, 1e-8f));
            float cz = Gw[wave][KTR][k] / fmaxf(n[KTR] * nk, 1e-8f);
            term = __logf(__expf(cz) + neg) - cz;
        }
        term += __shfl_xor(term, 1);
        term += __shfl_xor(term, 2);
        term += __shfl_xor(term, 4);
        term += __shfl_xor(term, 8);
        if (lane == 0) out[b0 + r] = term;
    }
}

extern "C" void kernel_launch(void* const* d_in, const int* in_sizes, int n_in,
                              void* d_out, int out_size, void* d_ws, size_t ws_size,
                              hipStream_t stream)
{
    const float* x   = (const float*)d_in[0];
    const float* Tw1 = (const float*)d_in[1];
    const float* Tb1 = (const float*)d_in[2];
    const float* Tw2 = (const float*)d_in[3];
    const float* Tb2 = (const float*)d_in[4];
    const float* Ew1 = (const float*)d_in[5];
    const float* Eb1 = (const float*)d_in[6];
    const float* Ew2 = (const float*)d_in[7];
    const float* Eb2 = (const float*)d_in[8];
    float* out = (float*)d_out;

    char* ws = (char*)d_ws;
    const size_t off_xb  = 0;
    const size_t off_tw1 = off_xb  + (size_t)BTOT * 256 * 2;   // 32 MB
    const size_t off_tw2 = off_tw1 + (size_t)KTR * 65536 * 2;
    const size_t off_ew1 = off_tw2 + (size_t)KTR * 65536 * 2;
    const size_t off_ew2 = off_ew1 + (size_t)65536 * 2;
    const size_t off_z   = off_ew2 + (size_t)65536 * 2;

    __hip_bfloat16* xb   = (__hip_bfloat16*)(ws + off_xb);
    __hip_bfloat16* Tw1t = (__hip_bfloat16*)(ws + off_tw1);
    __hip_bfloat16* Tw2t = (__hip_bfloat16*)(ws + off_tw2);
    __hip_bfloat16* Ew1t = (__hip_bfloat16*)(ws + off_ew1);
    __hip_bfloat16* Ew2t = (__hip_bfloat16*)(ws + off_ew2);
    __hip_bfloat16* zbuf = (__hip_bfloat16*)(ws + off_z);

    // single pass if scratch allows (~420 MB); chunk only as fallback
    long long zbytes = (long long)ws_size - (long long)off_z;
    long long rows_cap = zbytes > 0 ? zbytes / ((long long)NSLOT * 256 * 2) : 0;
    int chunk = (int)((rows_cap / 128) * 128);
    if (chunk > BTOT) chunk = BTOT;
    if (chunk < 128) chunk = 128;

    cast_x_kernel<<<dim3(BTOT * 256 / 1024), 256, 0, stream>>>(x, xb);
    transpose_cast_kernel<<<dim3(64, KTR), 256, 0, stream>>>(Tw1, Tw1t, 256, 256);
    transpose_cast_kernel<<<dim3(64, KTR), 256, 0, stream>>>(Tw2, Tw2t, 256, 256);
    transpose_cast_kernel<<<dim3(64, 1),   256, 0, stream>>>(Ew1, Ew1t, 256, 256);
    transpose_cast_kernel<<<dim3(64, 1),   256, 0, stream>>>(Ew2, Ew2t, 256, 256);

    for (int b0 = 0; b0 < BTOT; b0 += chunk) {
        int rows = (BTOT - b0 < chunk) ? (BTOT - b0) : chunk;
        chain_kernel<<<dim3(rows / 64, NSLOT), 256, 0, stream>>>(
            xb, Tw1t, Tb1, Tw2t, Tb2, Ew1t, Eb1, Ew2t, Eb2, zbuf, b0);
        reduce_kernel<<<dim3(4096), 256, 0, stream>>>(zbuf, out, b0, rows);
    }
}

// Round 3
// 893.905 us; speedup vs baseline: 1.1639x; 1.1639x over previous
//
#include <hip/hip_runtime.h>
#include <hip/hip_bf16.h>
#include <stdint.h>

#define BTOT  65536
#define KTR   11
#define NSLOT 12   // 11 transforms + z

typedef __attribute__((ext_vector_type(8))) short bf16x8_t;
typedef __attribute__((ext_vector_type(4))) float f32x4_t;

// Swizzled LDS layout: row m x 256 bf16 cols, 16B groups rotated by row so
// frag ds_read_b128 across 16 rows spreads banks (<=2-way, free per m136).
// Element offset. b64 sub-writes (n%8 in {0,4}) stay inside one group.
__device__ __forceinline__ int act_addr(int m, int n) {
    return m * 256 + ((((n >> 3) + m) & 31) << 3) + (n & 7);
}

// tanh-form gelu; |err| <~1e-3, invisible under bf16 storage noise.
__device__ __forceinline__ float gelu_fast(float x) {
    float x2 = x * x;
    float t2 = 1.5957691216057308f * x * fmaf(0.044715f, x2, 1.0f);
    float e  = __expf(fminf(t2, 30.f));
    return x * e * __builtin_amdgcn_rcpf(1.0f + e);
}

// generic fp32 -> bf16 cast, 4 elems/thread (also used for Tw2 cast)
__global__ void cast_x_kernel(const float* __restrict__ x, __hip_bfloat16* __restrict__ xb) {
    int i = (blockIdx.x * 256 + threadIdx.x) * 4;
    float4 v = *(const float4*)(x + i);
    union { __hip_bfloat16 h[4]; uint64_t u; } o;
    o.h[0] = __float2bfloat16(v.x);
    o.h[1] = __float2bfloat16(v.y);
    o.h[2] = __float2bfloat16(v.z);
    o.h[3] = __float2bfloat16(v.w);
    *(uint64_t*)(xb + i) = o.u;
}

// out[b][c][r] = in[b][r][c], cast fp32 -> bf16.
__global__ void transpose_cast_kernel(const float* __restrict__ in,
                                      __hip_bfloat16* __restrict__ out,
                                      int R, int C) {
    __shared__ float tile[32][33];
    int tpc = C >> 5;
    int tr = (blockIdx.x / tpc) << 5;
    int tc = (blockIdx.x % tpc) << 5;
    const float* bi = in + (size_t)blockIdx.y * R * C;
    __hip_bfloat16* bo = out + (size_t)blockIdx.y * R * C;
    int lx = threadIdx.x & 31, ly = threadIdx.x >> 5;
    #pragma unroll
    for (int r = 0; r < 32; r += 8)
        tile[ly + r][lx] = bi[(size_t)(tr + ly + r) * C + tc + lx];
    __syncthreads();
    #pragma unroll
    for (int r = 0; r < 32; r += 8)
        bo[(size_t)(tc + ly + r) * R + tr + lx] = __float2bfloat16(tile[lx][ly + r]);
}

// Fused weight: Wft[k][j][h] = sum_d Ew1t[j][d] * Tw2b[k][h][d]
// (= (Tw2[k] @ Ew1)^T, the [n][k] layout run_stage wants).
// Legal because there is NO nonlinearity between the Tw2 stage and the Ew1
// stage: tx = act1@Tw2+b2 is linear, so (act1@Tw2+b2)@Ew1+e1 =
// act1@(Tw2@Ew1) + (b2@Ew1+e1). Removes 11 of 46 chain stages (-24%).
// Same fragment mapping as run_stage (D row = A-row j, D col = B-row h).
__global__ void fuse_w_kernel(const __hip_bfloat16* __restrict__ Ew1t,
                              const __hip_bfloat16* __restrict__ Tw2b,
                              __hip_bfloat16* __restrict__ Wft)
{
    __shared__ __align__(16) __hip_bfloat16 bt[64 * 256];   // 64 h-rows of Tw2b[k]
    const int tid  = threadIdx.x;
    const int wave = tid >> 6, lane = tid & 63;
    const int lr = lane & 15, q = lane >> 4;
    const int k  = blockIdx.y;
    const int h0 = blockIdx.x << 6;
    const __hip_bfloat16* src = Tw2b + (size_t)k * 65536;

    #pragma unroll
    for (int i = 0; i < 8; ++i) {
        int lin = i * 256 + tid;
        int r = lin >> 5, g = lin & 31;
        bf16x8_t v = *(const bf16x8_t*)(src + (size_t)(h0 + r) * 256 + g * 8);
        *(bf16x8_t*)(bt + act_addr(r, g * 8)) = v;
    }
    __syncthreads();

    const int wc = wave << 6;
    f32x4_t acc[4][4];
    #pragma unroll
    for (int mt = 0; mt < 4; ++mt)
        #pragma unroll
        for (int nt = 0; nt < 4; ++nt)
            acc[mt][nt] = (f32x4_t){0.f, 0.f, 0.f, 0.f};

    #pragma unroll 1
    for (int kc = 0; kc < 8; ++kc) {
        const int kof = (kc << 5) + (q << 3);
        bf16x8_t a[4], b[4];
        #pragma unroll
        for (int mt = 0; mt < 4; ++mt)
            a[mt] = *(const bf16x8_t*)(Ew1t + (size_t)(wc + (mt << 4) + lr) * 256 + kof);
        #pragma unroll
        for (int nt = 0; nt < 4; ++nt)
            b[nt] = *(const bf16x8_t*)(bt + act_addr((nt << 4) + lr, kof));
        #pragma unroll
        for (int mt = 0; mt < 4; ++mt)
            #pragma unroll
            for (int nt = 0; nt < 4; ++nt)
                acc[mt][nt] = __builtin_amdgcn_mfma_f32_16x16x32_bf16(a[mt], b[nt], acc[mt][nt], 0, 0, 0);
    }

    __hip_bfloat16* dst = Wft + (size_t)k * 65536;
    #pragma unroll
    for (int mt = 0; mt < 4; ++mt)
        #pragma unroll
        for (int nt = 0; nt < 4; ++nt) {
            const int h = h0 + (nt << 4) + lr;
            #pragma unroll
            for (int r = 0; r < 4; ++r) {
                const int j = wc + (mt << 4) + (q << 2) + r;
                dst[(size_t)j * 256 + h] = __float2bfloat16(acc[mt][nt][r]);
            }
        }
}

// bf[k][j] = Eb1[j] + sum_d Tb2[k][d] * Ew1[d][j]   (fp32 throughout)
__global__ void fuse_b_kernel(const float* __restrict__ Tb2,
                              const float* __restrict__ Ew1,
                              const float* __restrict__ Eb1,
                              float* __restrict__ bf)
{
    const int k = blockIdx.x, j = threadIdx.x;
    float s = Eb1[j];
    #pragma unroll 4
    for (int d = 0; d < 256; ++d)
        s = fmaf(Tb2[k * 256 + d], Ew1[d * 256 + j], s);
    bf[k * 256 + j] = s;
}

// One stage: act[64][256] (LDS, swizzled) <- f(act @ W + bias).
// Operand-swapped MFMA: D = W^T (A-op, global L2-hot) x act^T (B-op, LDS).
// D row (q*4+r) = output col n -> 4 consecutive n per thread -> ds_write_b64.
// Wave w owns weight-col strip [w*64, +64) (4 m-tiles) x all 64 batch rows
// (4 n-tiles). M=64 tile: acc=64 AGPR, 32KB LDS -> 3 blocks/CU (12 waves),
// +50% latency hiding vs the M=128 variant (which was 20%-util latency-bound).
__device__ void run_stage(__hip_bfloat16* act,
                          const __hip_bfloat16* __restrict__ Wt,   // [n][k] row-major
                          const float* __restrict__ bias,
                          bool do_gelu, int wave, int lane)
{
    const int lr = lane & 15;
    const int q  = lane >> 4;
    const int wc = wave << 6;           // weight-col strip base

    f32x4_t acc[4][4];
    #pragma unroll
    for (int mt = 0; mt < 4; ++mt)
        #pragma unroll
        for (int nt = 0; nt < 4; ++nt)
            acc[mt][nt] = (f32x4_t){0.f, 0.f, 0.f, 0.f};

    // prefetch A-frags (weights) for kc=0
    bf16x8_t a[4];
    #pragma unroll
    for (int mt = 0; mt < 4; ++mt)
        a[mt] = *(const bf16x8_t*)(Wt + (size_t)(wc + (mt << 4) + lr) * 256 + (q << 3));

    #pragma unroll 1
    for (int kc = 0; kc < 8; ++kc) {
        const int kof = (kc << 5) + (q << 3);
        bf16x8_t an[4];
        if (kc < 7) {
            #pragma unroll
            for (int mt = 0; mt < 4; ++mt)
                an[mt] = *(const bf16x8_t*)(Wt + (size_t)(wc + (mt << 4) + lr) * 256 + kof + 32);
        }
        bf16x8_t b[4];
        #pragma unroll
        for (int nt = 0; nt < 4; ++nt)
            b[nt] = *(const bf16x8_t*)(act + act_addr((nt << 4) + lr, kof));
        #pragma unroll
        for (int mt = 0; mt < 4; ++mt)
            #pragma unroll
            for (int nt = 0; nt < 4; ++nt)
                acc[mt][nt] = __builtin_amdgcn_mfma_f32_16x16x32_bf16(a[mt], b[nt], acc[mt][nt], 0, 0, 0);
        if (kc < 7) {
            #pragma unroll
            for (int mt = 0; mt < 4; ++mt) a[mt] = an[mt];
        }
    }

    __syncthreads();   // all waves done reading act before overwrite
    #pragma unroll
    for (int mt = 0; mt < 4; ++mt) {
        const int nbase = wc + (mt << 4) + (q << 2);
        const float4 bv = *(const float4*)(bias + nbase);
        #pragma unroll
        for (int nt = 0; nt < 4; ++nt) {
            const int row = (nt << 4) + lr;
            union { __hip_bfloat16 h[4]; uint64_t u; } o;
            #pragma unroll
            for (int r = 0; r < 4; ++r) {
                float v = acc[mt][nt][r] + ((const float*)&bv)[r];
                if (do_gelu) v = gelu_fast(v);
                o.h[r] = __float2bfloat16(v);
            }
            *(uint64_t*)(act + act_addr(row, nbase)) = o.u;
        }
    }
    __syncthreads();
}

__launch_bounds__(256, 3)
__global__ void chain_kernel(const __hip_bfloat16* __restrict__ xb,
                             const __hip_bfloat16* __restrict__ Tw1t,
                             const float* __restrict__ Tb1,
                             const __hip_bfloat16* __restrict__ Wft,
                             const float* __restrict__ bfb,
                             const __hip_bfloat16* __restrict__ Ew1t,
                             const float* __restrict__ Eb1,
                             const __hip_bfloat16* __restrict__ Ew2t,
                             const float* __restrict__ Eb2,
                             __hip_bfloat16* __restrict__ zbuf,
                             int b0)
{
    __shared__ __align__(16) __hip_bfloat16 act[64 * 256];   // 32 KB
    const int tid  = threadIdx.x;
    const int wave = tid >> 6, lane = tid & 63;
    const int slot = blockIdx.y;
    const int tile = blockIdx.x;

    // stage x tile (64 rows) into LDS
    #pragma unroll
    for (int i = 0; i < 8; ++i) {
        int lin = i * 256 + tid;
        int r = lin >> 5, g = lin & 31;
        bf16x8_t v = *(const bf16x8_t*)(xb + (size_t)(b0 + tile * 64 + r) * 256 + g * 8);
        *(bf16x8_t*)(act + act_addr(r, g * 8)) = v;
    }
    __syncthreads();

    if (slot < KTR) {
        // T-slot: gelu(x@Tw1+b1) -> gelu(. @ Wf + bf) -> . @ Ew2 + e2
        run_stage(act, Tw1t + (size_t)slot * 65536, Tb1 + slot * 256, true, wave, lane);
        run_stage(act, Wft  + (size_t)slot * 65536, bfb + slot * 256, true, wave, lane);
    } else {
        // z-slot: gelu(x@Ew1+e1) -> . @ Ew2 + e2
        run_stage(act, Ew1t, Eb1, true, wave, lane);
    }
    run_stage(act, Ew2t, Eb2, false, wave, lane);

    // interleaved zbuf: [row][slot][256]
    __hip_bfloat16* dst = zbuf + ((size_t)(tile * 64) * NSLOT + slot) * 256;
    #pragma unroll
    for (int i = 0; i < 8; ++i) {
        int lin = i * 256 + tid;
        int r = lin >> 5, g = lin & 31;
        bf16x8_t v = *(const bf16x8_t*)(act + act_addr(r, g * 8));
        *(bf16x8_t*)(dst + (size_t)r * NSLOT * 256 + g * 8) = v;
    }
}

// Per row: G = Z Z^T (12x12 over H=256) via mfma(v,v,acc), A-frag == B-frag.
// One row per WAVE, fragments loaded DIRECTLY from global (zbuf's
// [row][slot][256] layout puts a row's whole Gram operand in 6144 contiguous
// bytes; lane(lr,q) reads slot*512 + kc*64 + q*16 -> 64B-granule coalesced,
// full line coverage over the kc loop). No staging LDS, no barrier; only the
// 4.3KB wave-local Gw scratch (within-wave RAW ordered by lgkmcnt).
__launch_bounds__(256, 4)
__global__ void reduce_kernel(const __hip_bfloat16* __restrict__ zbuf,
                              float* __restrict__ out, int b0, int nrows)
{
    __shared__ float Gw[4][16][17];
    const int tid  = threadIdx.x;
    const int wave = tid >> 6, lane = tid & 63;
    const int lr = lane & 15, q = lane >> 4;
    const int slot = lr < NSLOT ? lr : NSLOT - 1;   // lanes 12-15 broadcast slot 11
    const int nw = gridDim.x * 4;                    // total waves
    const size_t lanoff = (size_t)slot * 256 + (q << 3);

    #pragma unroll 1
    for (int r = blockIdx.x * 4 + wave; r < nrows; r += nw) {
        const __hip_bfloat16* zr = zbuf + (size_t)r * (NSLOT * 256) + lanoff;
        bf16x8_t v[8];
        #pragma unroll
        for (int kc = 0; kc < 8; ++kc)
            v[kc] = *(const bf16x8_t*)(zr + kc * 32);

        f32x4_t acc = (f32x4_t){0.f, 0.f, 0.f, 0.f};
        #pragma unroll
        for (int kc = 0; kc < 8; ++kc)
            acc = __builtin_amdgcn_mfma_f32_16x16x32_bf16(v[kc], v[kc], acc, 0, 0, 0);

        #pragma unroll
        for (int rr = 0; rr < 4; ++rr)
            Gw[wave][(q << 2) + rr][lr] = acc[rr];
        // wave-local RAW on Gw: hardware/compiler waitcnt orders it; no barrier
        float term = 0.f;
        if (lane < 11) {
            const int k = lane;
            float n[NSLOT];
            #pragma unroll
            for (int l = 0; l < NSLOT; ++l) n[l] = sqrtf(Gw[wave][l][l]);
            const float nk = n[k];
            float neg = 0.f;
            #pragma unroll
            for (int l = 0; l < KTR; ++l)
                if (l != k)
                    neg += __expf(Gw[wave][l][k] / fmaxf(n[l] * nk, 1e-8f));
            float cz = Gw[wave][KTR][k] / fmaxf(n[KTR] * nk, 1e-8f);
            term = __logf(__expf(cz) + neg) - cz;
        }
        term += __shfl_xor(term, 1);
        term += __shfl_xor(term, 2);
        term += __shfl_xor(term, 4);
        term += __shfl_xor(term, 8);
        if (lane == 0) out[b0 + r] = term;
    }
}

extern "C" void kernel_launch(void* const* d_in, const int* in_sizes, int n_in,
                              void* d_out, int out_size, void* d_ws, size_t ws_size,
                              hipStream_t stream)
{
    const float* x   = (const float*)d_in[0];
    const float* Tw1 = (const float*)d_in[1];
    const float* Tb1 = (const float*)d_in[2];
    const float* Tw2 = (const float*)d_in[3];
    const float* Tb2 = (const float*)d_in[4];
    const float* Ew1 = (const float*)d_in[5];
    const float* Eb1 = (const float*)d_in[6];
    const float* Ew2 = (const float*)d_in[7];
    const float* Eb2 = (const float*)d_in[8];
    float* out = (float*)d_out;

    char* ws = (char*)d_ws;
    const size_t off_xb   = 0;
    const size_t off_tw1  = off_xb   + (size_t)BTOT * 256 * 2;     // 32 MB
    const size_t off_wf   = off_tw1  + (size_t)KTR * 65536 * 2;
    const size_t off_ew1  = off_wf   + (size_t)KTR * 65536 * 2;
    const size_t off_ew2  = off_ew1  + (size_t)65536 * 2;
    const size_t off_tw2b = off_ew2  + (size_t)65536 * 2;
    const size_t off_bf   = off_tw2b + (size_t)KTR * 65536 * 2;
    const size_t off_z    = off_bf   + (size_t)KTR * 256 * 4;

    __hip_bfloat16* xb   = (__hip_bfloat16*)(ws + off_xb);
    __hip_bfloat16* Tw1t = (__hip_bfloat16*)(ws + off_tw1);
    __hip_bfloat16* Wft  = (__hip_bfloat16*)(ws + off_wf);
    __hip_bfloat16* Ew1t = (__hip_bfloat16*)(ws + off_ew1);
    __hip_bfloat16* Ew2t = (__hip_bfloat16*)(ws + off_ew2);
    __hip_bfloat16* Tw2b = (__hip_bfloat16*)(ws + off_tw2b);
    float*          bfb  = (float*)(ws + off_bf);
    __hip_bfloat16* zbuf = (__hip_bfloat16*)(ws + off_z);

    // single pass if scratch allows (~440 MB); chunk only as fallback
    long long zbytes = (long long)ws_size - (long long)off_z;
    long long rows_cap = zbytes > 0 ? zbytes / ((long long)NSLOT * 256 * 2) : 0;
    int chunk = (int)((rows_cap / 128) * 128);
    if (chunk > BTOT) chunk = BTOT;
    if (chunk < 128) chunk = 128;

    cast_x_kernel<<<dim3(BTOT * 256 / 1024), 256, 0, stream>>>(x, xb);
    cast_x_kernel<<<dim3(KTR * 65536 / 1024), 256, 0, stream>>>(Tw2, Tw2b);
    transpose_cast_kernel<<<dim3(64, KTR), 256, 0, stream>>>(Tw1, Tw1t, 256, 256);
    transpose_cast_kernel<<<dim3(64, 1),   256, 0, stream>>>(Ew1, Ew1t, 256, 256);
    transpose_cast_kernel<<<dim3(64, 1),   256, 0, stream>>>(Ew2, Ew2t, 256, 256);
    fuse_b_kernel<<<dim3(KTR), 256, 0, stream>>>(Tb2, Ew1, Eb1, bfb);
    fuse_w_kernel<<<dim3(4, KTR), 256, 0, stream>>>(Ew1t, Tw2b, Wft);

    for (int b0 = 0; b0 < BTOT; b0 += chunk) {
        int rows = (BTOT - b0 < chunk) ? (BTOT - b0) : chunk;
        chain_kernel<<<dim3(rows / 64, NSLOT), 256, 0, stream>>>(
            xb, Tw1t, Tb1, Wft, bfb, Ew1t, Eb1, Ew2t, Eb2, zbuf, b0);
        reduce_kernel<<<dim3(4096), 256, 0, stream>>>(zbuf, out, b0, rows);
    }
}

// Round 5
// 871.914 us; speedup vs baseline: 1.1933x; 1.0252x over previous
//
#include <hip/hip_runtime.h>
#include <hip/hip_bf16.h>
#include <stdint.h>

#define BTOT  65536
#define KTR   11
#define NSLOT 12   // 11 transforms + z

typedef __attribute__((ext_vector_type(8))) short bf16x8_t;
typedef __attribute__((ext_vector_type(4))) float f32x4_t;

// Swizzled LDS layout: row m x 256 bf16 cols, 16B groups rotated by row so
// frag ds_read_b128 across 16 rows spreads banks (<=2-way, free per m136).
__device__ __forceinline__ int act_addr(int m, int n) {
    return m * 256 + ((((n >> 3) + m) & 31) << 3) + (n & 7);
}

// tanh-form gelu, exp2-native: log2(e) folded into the 1.59576912 constant
// (saves one mul/value vs __expf). |err| <~1e-3, invisible under bf16 noise.
__device__ __forceinline__ float gelu_fast(float x) {
    float x2 = x * x;
    float t2 = 2.3022083f * x * fmaf(0.044715f, x2, 1.0f);   // 1.5957691*log2e
    float e  = exp2f(fminf(t2, 44.f));
    return x * e * __builtin_amdgcn_rcpf(1.0f + e);
}

// generic fp32 -> bf16 cast, 4 elems/thread (also used for Tw2 cast)
__global__ void cast_x_kernel(const float* __restrict__ x, __hip_bfloat16* __restrict__ xb) {
    int i = (blockIdx.x * 256 + threadIdx.x) * 4;
    float4 v = *(const float4*)(x + i);
    union { __hip_bfloat16 h[4]; uint64_t u; } o;
    o.h[0] = __float2bfloat16(v.x);
    o.h[1] = __float2bfloat16(v.y);
    o.h[2] = __float2bfloat16(v.z);
    o.h[3] = __float2bfloat16(v.w);
    *(uint64_t*)(xb + i) = o.u;
}

// out[b][c][r] = in[b][r][c], cast fp32 -> bf16.
__global__ void transpose_cast_kernel(const float* __restrict__ in,
                                      __hip_bfloat16* __restrict__ out,
                                      int R, int C) {
    __shared__ float tile[32][33];
    int tpc = C >> 5;
    int tr = (blockIdx.x / tpc) << 5;
    int tc = (blockIdx.x % tpc) << 5;
    const float* bi = in + (size_t)blockIdx.y * R * C;
    __hip_bfloat16* bo = out + (size_t)blockIdx.y * R * C;
    int lx = threadIdx.x & 31, ly = threadIdx.x >> 5;
    #pragma unroll
    for (int r = 0; r < 32; r += 8)
        tile[ly + r][lx] = bi[(size_t)(tr + ly + r) * C + tc + lx];
    __syncthreads();
    #pragma unroll
    for (int r = 0; r < 32; r += 8)
        bo[(size_t)(tc + ly + r) * R + tr + lx] = __float2bfloat16(tile[lx][ly + r]);
}

// Fused weight: Wft[k][j][h] = sum_d Ew1t[j][d] * Tw2b[k][h][d]
// (= (Tw2[k] @ Ew1)^T). Legal: no nonlinearity between Tw2 and Ew1 stages.
__global__ void fuse_w_kernel(const __hip_bfloat16* __restrict__ Ew1t,
                              const __hip_bfloat16* __restrict__ Tw2b,
                              __hip_bfloat16* __restrict__ Wft)
{
    __shared__ __align__(16) __hip_bfloat16 bt[64 * 256];
    const int tid  = threadIdx.x;
    const int wave = tid >> 6, lane = tid & 63;
    const int lr = lane & 15, q = lane >> 4;
    const int k  = blockIdx.y;
    const int h0 = blockIdx.x << 6;
    const __hip_bfloat16* src = Tw2b + (size_t)k * 65536;

    #pragma unroll
    for (int i = 0; i < 8; ++i) {
        int lin = i * 256 + tid;
        int r = lin >> 5, g = lin & 31;
        bf16x8_t v = *(const bf16x8_t*)(src + (size_t)(h0 + r) * 256 + g * 8);
        *(bf16x8_t*)(bt + act_addr(r, g * 8)) = v;
    }
    __syncthreads();

    const int wc = wave << 6;
    f32x4_t acc[4][4];
    #pragma unroll
    for (int mt = 0; mt < 4; ++mt)
        #pragma unroll
        for (int nt = 0; nt < 4; ++nt)
            acc[mt][nt] = (f32x4_t){0.f, 0.f, 0.f, 0.f};

    #pragma unroll 1
    for (int kc = 0; kc < 8; ++kc) {
        const int kof = (kc << 5) + (q << 3);
        bf16x8_t a[4], b[4];
        #pragma unroll
        for (int mt = 0; mt < 4; ++mt)
            a[mt] = *(const bf16x8_t*)(Ew1t + (size_t)(wc + (mt << 4) + lr) * 256 + kof);
        #pragma unroll
        for (int nt = 0; nt < 4; ++nt)
            b[nt] = *(const bf16x8_t*)(bt + act_addr((nt << 4) + lr, kof));
        #pragma unroll
        for (int mt = 0; mt < 4; ++mt)
            #pragma unroll
            for (int nt = 0; nt < 4; ++nt)
                acc[mt][nt] = __builtin_amdgcn_mfma_f32_16x16x32_bf16(a[mt], b[nt], acc[mt][nt], 0, 0, 0);
    }

    __hip_bfloat16* dst = Wft + (size_t)k * 65536;
    #pragma unroll
    for (int mt = 0; mt < 4; ++mt)
        #pragma unroll
        for (int nt = 0; nt < 4; ++nt) {
            const int h = h0 + (nt << 4) + lr;
            #pragma unroll
            for (int r = 0; r < 4; ++r) {
                const int j = wc + (mt << 4) + (q << 2) + r;
                dst[(size_t)j * 256 + h] = __float2bfloat16(acc[mt][nt][r]);
            }
        }
}

// bf[k][j] = Eb1[j] + sum_d Tb2[k][d] * Ew1[d][j]   (fp32 throughout)
__global__ void fuse_b_kernel(const float* __restrict__ Tb2,
                              const float* __restrict__ Ew1,
                              const float* __restrict__ Eb1,
                              float* __restrict__ bf)
{
    const int k = blockIdx.x, j = threadIdx.x;
    float s = Eb1[j];
    #pragma unroll 4
    for (int d = 0; d < 256; ++d)
        s = fmaf(Tb2[k * 256 + d], Ew1[d * 256 + j], s);
    bf[k * 256 + j] = s;
}

// One stage: act[64][256] (LDS, swizzled) <- f(act @ W + bias).
// Operand-swapped MFMA: D = W^T (A-op, global L2-hot) x act^T (B-op, LDS).
// Bias is folded into the MFMA C-init (removes 64 epilogue adds/thread);
// DO_GELU is a template param so the branch folds at compile time.
template<bool DO_GELU>
__device__ void run_stage(__hip_bfloat16* act,
                          const __hip_bfloat16* __restrict__ Wt,   // [n][k] row-major
                          const float* __restrict__ bias,
                          int wave, int lane)
{
    const int lr = lane & 15;
    const int q  = lane >> 4;
    const int wc = wave << 6;           // weight-col strip base

    // init acc with bias: D row (q*4+r) = output col n = wc+mt*16+q*4+r,
    // identical for all nt (batch) -> broadcast bv[r].
    f32x4_t acc[4][4];
    #pragma unroll
    for (int mt = 0; mt < 4; ++mt) {
        const float4 bv = *(const float4*)(bias + wc + (mt << 4) + (q << 2));
        #pragma unroll
        for (int nt = 0; nt < 4; ++nt)
            acc[mt][nt] = (f32x4_t){bv.x, bv.y, bv.z, bv.w};
    }

    // prefetch A-frags (weights) for kc=0
    bf16x8_t a[4];
    #pragma unroll
    for (int mt = 0; mt < 4; ++mt)
        a[mt] = *(const bf16x8_t*)(Wt + (size_t)(wc + (mt << 4) + lr) * 256 + (q << 3));

    #pragma unroll 1
    for (int kc = 0; kc < 8; ++kc) {
        const int kof = (kc << 5) + (q << 3);
        bf16x8_t an[4];
        if (kc < 7) {
            #pragma unroll
            for (int mt = 0; mt < 4; ++mt)
                an[mt] = *(const bf16x8_t*)(Wt + (size_t)(wc + (mt << 4) + lr) * 256 + kof + 32);
        }
        bf16x8_t b[4];
        #pragma unroll
        for (int nt = 0; nt < 4; ++nt)
            b[nt] = *(const bf16x8_t*)(act + act_addr((nt << 4) + lr, kof));
        #pragma unroll
        for (int mt = 0; mt < 4; ++mt)
            #pragma unroll
            for (int nt = 0; nt < 4; ++nt)
                acc[mt][nt] = __builtin_amdgcn_mfma_f32_16x16x32_bf16(a[mt], b[nt], acc[mt][nt], 0, 0, 0);
        if (kc < 7) {
            #pragma unroll
            for (int mt = 0; mt < 4; ++mt) a[mt] = an[mt];
        }
    }

    __syncthreads();   // all waves done reading act before overwrite
    #pragma unroll
    for (int mt = 0; mt < 4; ++mt) {
        const int nbase = wc + (mt << 4) + (q << 2);
        #pragma unroll
        for (int nt = 0; nt < 4; ++nt) {
            const int row = (nt << 4) + lr;
            union { __hip_bfloat16 h[4]; uint64_t u; } o;
            #pragma unroll
            for (int r = 0; r < 4; ++r) {
                float v = acc[mt][nt][r];
                if (DO_GELU) v = gelu_fast(v);
                o.h[r] = __float2bfloat16(v);
            }
            *(uint64_t*)(act + act_addr(row, nbase)) = o.u;
        }
    }
    __syncthreads();
}

__launch_bounds__(256, 3)
__global__ void chain_kernel(const __hip_bfloat16* __restrict__ xb,
                             const __hip_bfloat16* __restrict__ Tw1t,
                             const float* __restrict__ Tb1,
                             const __hip_bfloat16* __restrict__ Wft,
                             const float* __restrict__ bfb,
                             const __hip_bfloat16* __restrict__ Ew1t,
                             const float* __restrict__ Eb1,
                             const __hip_bfloat16* __restrict__ Ew2t,
                             const float* __restrict__ Eb2,
                             __hip_bfloat16* __restrict__ zbuf,
                             int b0)
{
    __shared__ __align__(16) __hip_bfloat16 act[64 * 256];   // 32 KB
    const int tid  = threadIdx.x;
    const int wave = tid >> 6, lane = tid & 63;
    const int slot = blockIdx.y;
    const int tile = blockIdx.x;

    // stage x tile (64 rows) into LDS
    #pragma unroll
    for (int i = 0; i < 8; ++i) {
        int lin = i * 256 + tid;
        int r = lin >> 5, g = lin & 31;
        bf16x8_t v = *(const bf16x8_t*)(xb + (size_t)(b0 + tile * 64 + r) * 256 + g * 8);
        *(bf16x8_t*)(act + act_addr(r, g * 8)) = v;
    }
    __syncthreads();

    if (slot < KTR) {
        // T-slot: gelu(x@Tw1+b1) -> gelu(. @ Wf + bf) -> . @ Ew2 + e2
        run_stage<true>(act, Tw1t + (size_t)slot * 65536, Tb1 + slot * 256, wave, lane);
        run_stage<true>(act, Wft  + (size_t)slot * 65536, bfb + slot * 256, wave, lane);
    } else {
        // z-slot: gelu(x@Ew1+e1) -> . @ Ew2 + e2
        run_stage<true>(act, Ew1t, Eb1, wave, lane);
    }
    run_stage<false>(act, Ew2t, Eb2, wave, lane);

    // interleaved zbuf: [row][slot][256]
    __hip_bfloat16* dst = zbuf + ((size_t)(tile * 64) * NSLOT + slot) * 256;
    #pragma unroll
    for (int i = 0; i < 8; ++i) {
        int lin = i * 256 + tid;
        int r = lin >> 5, g = lin & 31;
        bf16x8_t v = *(const bf16x8_t*)(act + act_addr(r, g * 8));
        *(bf16x8_t*)(dst + (size_t)r * NSLOT * 256 + g * 8) = v;
    }
}

// Per row: G = Z Z^T (12x12 over H=256) via mfma(v,v,acc), A-frag == B-frag.
// v3: 8 contiguous rows per wave with a 2-deep row pipeline (next row's 8
// global loads issue BEFORE current row's MFMA/tail -> HBM latency hides
// under compute), and the tail's ~23 IEEE divides replaced by 12 rcp + muls
// (norms are O(1-30) >> eps, so max(n*n,1e-8) semantics preserved via
// rcp(max(n,1e-4))). Grid = rows/32 exactly; no bound checks.
#define ROW_BODY(V, I)                                                        \
    {                                                                         \
        f32x4_t acc = (f32x4_t){0.f, 0.f, 0.f, 0.f};                          \
        _Pragma("unroll")                                                     \
        for (int kc = 0; kc < 8; ++kc)                                        \
            acc = __builtin_amdgcn_mfma_f32_16x16x32_bf16(V[kc], V[kc], acc, 0, 0, 0); \
        _Pragma("unroll")                                                     \
        for (int rr = 0; rr < 4; ++rr)                                        \
            Gw[wave][(q << 2) + rr][lr] = acc[rr];                            \
        float term = 0.f;                                                     \
        if (lane < 11) {                                                      \
            const int k = lane;                                               \
            float nr[NSLOT];                                                  \
            _Pragma("unroll")                                                 \
            for (int l = 0; l < NSLOT; ++l)                                   \
                nr[l] = __builtin_amdgcn_rcpf(fmaxf(sqrtf(Gw[wave][l][l]), 1e-4f)); \
            const float nrk = nr[k];                                          \
            float neg = 0.f;                                                  \
            _Pragma("unroll")                                                 \
            for (int l = 0; l < KTR; ++l)                                     \
                if (l != k)                                                   \
                    neg += __expf(Gw[wave][l][k] * nr[l] * nrk);              \
            float cz = Gw[wave][KTR][k] * nr[KTR] * nrk;                      \
            term = __logf(__expf(cz) + neg) - cz;                             \
        }                                                                     \
        term += __shfl_xor(term, 1);                                          \
        term += __shfl_xor(term, 2);                                          \
        term += __shfl_xor(term, 4);                                          \
        term += __shfl_xor(term, 8);                                          \
        if (lane == 0) out[b0 + r0 + (I)] = term;                             \
    }

__launch_bounds__(256, 4)
__global__ void reduce_kernel(const __hip_bfloat16* __restrict__ zbuf,
                              float* __restrict__ out, int b0)
{
    __shared__ float Gw[4][16][17];
    const int tid  = threadIdx.x;
    const int wave = tid >> 6, lane = tid & 63;
    const int lr = lane & 15, q = lane >> 4;
    const int slot = lr < NSLOT ? lr : NSLOT - 1;   // lanes 12-15 broadcast slot 11
    const size_t lanoff = (size_t)slot * 256 + (q << 3);

    const int r0 = (blockIdx.x * 4 + wave) * 8;     // 8 contiguous rows per wave
    const __hip_bfloat16* zr = zbuf + (size_t)r0 * (NSLOT * 256) + lanoff;

    bf16x8_t va[8], vb[8];
    #pragma unroll
    for (int kc = 0; kc < 8; ++kc)
        va[kc] = *(const bf16x8_t*)(zr + kc * 32);

    #pragma unroll 1
    for (int i2 = 0; i2 < 4; ++i2) {
        const int ie = i2 * 2;
        {   // even row: consume va, prefetch row ie+1 into vb (always valid)
            const __hip_bfloat16* zn = zr + (size_t)(ie + 1) * (NSLOT * 256);
            #pragma unroll
            for (int kc = 0; kc < 8; ++kc)
                vb[kc] = *(const bf16x8_t*)(zn + kc * 32);
            ROW_BODY(va, ie)
        }
        {   // odd row: consume vb, prefetch row ie+2 into va (guarded: last row has none)
            if (ie + 2 < 8) {
                const __hip_bfloat16* zn = zr + (size_t)(ie + 2) * (NSLOT * 256);
                #pragma unroll
                for (int kc = 0; kc < 8; ++kc)
                    va[kc] = *(const bf16x8_t*)(zn + kc * 32);
            }
            ROW_BODY(vb, ie + 1)
        }
    }
}

extern "C" void kernel_launch(void* const* d_in, const int* in_sizes, int n_in,
                              void* d_out, int out_size, void* d_ws, size_t ws_size,
                              hipStream_t stream)
{
    const float* x   = (const float*)d_in[0];
    const float* Tw1 = (const float*)d_in[1];
    const float* Tb1 = (const float*)d_in[2];
    const float* Tw2 = (const float*)d_in[3];
    const float* Tb2 = (const float*)d_in[4];
    const float* Ew1 = (const float*)d_in[5];
    const float* Eb1 = (const float*)d_in[6];
    const float* Ew2 = (const float*)d_in[7];
    const float* Eb2 = (const float*)d_in[8];
    float* out = (float*)d_out;

    char* ws = (char*)d_ws;
    const size_t off_xb   = 0;
    const size_t off_tw1  = off_xb   + (size_t)BTOT * 256 * 2;     // 32 MB
    const size_t off_wf   = off_tw1  + (size_t)KTR * 65536 * 2;
    const size_t off_ew1  = off_wf   + (size_t)KTR * 65536 * 2;
    const size_t off_ew2  = off_ew1  + (size_t)65536 * 2;
    const size_t off_tw2b = off_ew2  + (size_t)65536 * 2;
    const size_t off_bf   = off_tw2b + (size_t)KTR * 65536 * 2;
    const size_t off_z    = off_bf   + (size_t)KTR * 256 * 4;

    __hip_bfloat16* xb   = (__hip_bfloat16*)(ws + off_xb);
    __hip_bfloat16* Tw1t = (__hip_bfloat16*)(ws + off_tw1);
    __hip_bfloat16* Wft  = (__hip_bfloat16*)(ws + off_wf);
    __hip_bfloat16* Ew1t = (__hip_bfloat16*)(ws + off_ew1);
    __hip_bfloat16* Ew2t = (__hip_bfloat16*)(ws + off_ew2);
    __hip_bfloat16* Tw2b = (__hip_bfloat16*)(ws + off_tw2b);
    float*          bfb  = (float*)(ws + off_bf);
    __hip_bfloat16* zbuf = (__hip_bfloat16*)(ws + off_z);

    // single pass if scratch allows (~440 MB); chunk only as fallback
    long long zbytes = (long long)ws_size - (long long)off_z;
    long long rows_cap = zbytes > 0 ? zbytes / ((long long)NSLOT * 256 * 2) : 0;
    int chunk = (int)((rows_cap / 128) * 128);
    if (chunk > BTOT) chunk = BTOT;
    if (chunk < 128) chunk = 128;

    cast_x_kernel<<<dim3(BTOT * 256 / 1024), 256, 0, stream>>>(x, xb);
    cast_x_kernel<<<dim3(KTR * 65536 / 1024), 256, 0, stream>>>(Tw2, Tw2b);
    transpose_cast_kernel<<<dim3(64, KTR), 256, 0, stream>>>(Tw1, Tw1t, 256, 256);
    transpose_cast_kernel<<<dim3(64, 1),   256, 0, stream>>>(Ew1, Ew1t, 256, 256);
    transpose_cast_kernel<<<dim3(64, 1),   256, 0, stream>>>(Ew2, Ew2t, 256, 256);
    fuse_b_kernel<<<dim3(KTR), 256, 0, stream>>>(Tb2, Ew1, Eb1, bfb);
    fuse_w_kernel<<<dim3(4, KTR), 256, 0, stream>>>(Ew1t, Tw2b, Wft);

    for (int b0 = 0; b0 < BTOT; b0 += chunk) {
        int rows = (BTOT - b0 < chunk) ? (BTOT - b0) : chunk;
        chain_kernel<<<dim3(rows / 64, NSLOT), 256, 0, stream>>>(
            xb, Tw1t, Tb1, Wft, bfb, Ew1t, Eb1, Ew2t, Eb2, zbuf, b0);
        reduce_kernel<<<dim3(rows / 32), 256, 0, stream>>>(zbuf, out, b0);
    }
}